// Round 1
// baseline (207.541 us; speedup 1.0000x reference)
//
#include <hip/hip_runtime.h>

#define VOCAB 128000
#define DIM 2048
#define NTOK 8192

// ---------------------------------------------------------------------------
// Kernel 1: dynamic absmax int8 fake-quant of x -> xq (in workspace)
// Single block, 256 threads. 2048 elements.
// ---------------------------------------------------------------------------
__global__ __launch_bounds__(256) void quant_act_kernel(
    const float* __restrict__ x, float* __restrict__ xq) {
  const int tid = threadIdx.x;
  float m = 0.0f;
  for (int i = tid; i < DIM; i += 256) m = fmaxf(m, fabsf(x[i]));
  // wave reduce (64 lanes)
  #pragma unroll
  for (int off = 32; off > 0; off >>= 1) m = fmaxf(m, __shfl_down(m, off, 64));

  __shared__ float smax[4];
  __shared__ float sscale;
  const int wid = tid >> 6;
  if ((tid & 63) == 0) smax[wid] = m;
  __syncthreads();
  if (tid == 0) {
    float mm = fmaxf(fmaxf(smax[0], smax[1]), fmaxf(smax[2], smax[3]));
    float scale = mm / 127.0f;
    scale = fmaxf(scale, 1e-12f);
    sscale = scale;
  }
  __syncthreads();
  const float scale = sscale;
  for (int i = tid; i < DIM; i += 256) {
    float q = rintf(x[i] / scale);          // rintf == round-half-even == jnp.round
    q = fminf(fmaxf(q, -128.0f), 127.0f);
    xq[i] = q * scale;
  }
}

__device__ __forceinline__ float qclip(float w) {
  return fminf(fmaxf(rintf(w), -128.0f), 127.0f);
}

// ---------------------------------------------------------------------------
// Kernel 2: embed gather. One block per token; float4 row streaming.
// out[t, :] = qclip(W[tok, :]) * scales[tok]
// ---------------------------------------------------------------------------
__global__ __launch_bounds__(256) void embed_kernel(
    const float* __restrict__ W, const float* __restrict__ scales,
    const int* __restrict__ tokens, float* __restrict__ out) {
  const int t = blockIdx.x;
  const int tok = tokens[t];
  const float s = scales[tok];
  const float4* __restrict__ wrow =
      reinterpret_cast<const float4*>(W + (size_t)tok * DIM);
  float4* __restrict__ orow = reinterpret_cast<float4*>(out + (size_t)t * DIM);
  #pragma unroll
  for (int k = 0; k < DIM / 4 / 256; ++k) {
    const int i = threadIdx.x + k * 256;
    float4 w4 = wrow[i];
    float4 r;
    r.x = qclip(w4.x) * s;
    r.y = qclip(w4.y) * s;
    r.z = qclip(w4.z) * s;
    r.w = qclip(w4.w) * s;
    orow[i] = r;
  }
}

// ---------------------------------------------------------------------------
// Kernel 3: readout GEMV. One wave per vocab row, 4 waves per block.
// out[row] = scales[row] * dot(qclip(W[row,:]), xq)
// Each lane: 8 coalesced float4 loads (lane-interleaved), fp32 accumulate,
// shfl tree reduce across the wave.
// ---------------------------------------------------------------------------
__global__ __launch_bounds__(256) void readout_kernel(
    const float* __restrict__ W, const float* __restrict__ scales,
    const float* __restrict__ xq, float* __restrict__ out) {
  const int wid = threadIdx.x >> 6;
  const int lane = threadIdx.x & 63;
  const int row = blockIdx.x * 4 + wid;
  if (row >= VOCAB) return;

  const float4* __restrict__ wrow =
      reinterpret_cast<const float4*>(W + (size_t)row * DIM);
  const float4* __restrict__ xv = reinterpret_cast<const float4*>(xq);

  float acc = 0.0f;
  #pragma unroll
  for (int k = 0; k < DIM / 4 / 64; ++k) {   // 8 iterations
    const int i = lane + k * 64;
    float4 w4 = wrow[i];
    float4 x4 = xv[i];
    acc += qclip(w4.x) * x4.x;
    acc += qclip(w4.y) * x4.y;
    acc += qclip(w4.z) * x4.z;
    acc += qclip(w4.w) * x4.w;
  }
  #pragma unroll
  for (int off = 32; off > 0; off >>= 1) acc += __shfl_down(acc, off, 64);
  if (lane == 0) out[row] = acc * scales[row];
}

// ---------------------------------------------------------------------------
extern "C" void kernel_launch(void* const* d_in, const int* in_sizes, int n_in,
                              void* d_out, int out_size, void* d_ws, size_t ws_size,
                              hipStream_t stream) {
  const float* W      = (const float*)d_in[0];   // [VOCAB, DIM]
  const float* scales = (const float*)d_in[1];   // [VOCAB]
  const int*   tokens = (const int*)d_in[2];     // [NTOK]
  const float* x      = (const float*)d_in[3];   // [DIM]

  float* out_embed   = (float*)d_out;                         // [NTOK, DIM]
  float* out_readout = (float*)d_out + (size_t)NTOK * DIM;    // [VOCAB]
  float* xq          = (float*)d_ws;                          // [DIM] scratch

  quant_act_kernel<<<1, 256, 0, stream>>>(x, xq);
  embed_kernel<<<NTOK, 256, 0, stream>>>(W, scales, tokens, out_embed);
  readout_kernel<<<VOCAB / 4, 256, 0, stream>>>(W, scales, xq, out_readout);
}

// Round 2
// 200.766 us; speedup vs baseline: 1.0337x; 1.0337x over previous
//
#include <hip/hip_runtime.h>

#define VOCAB 128000
#define DIM 2048
#define NTOK 8192

#define EMB_BLOCKS NTOK                      // 8192: one block per token
#define RO_BLOCKS (VOCAB / 4)                // 32000: 4 rows/block (1 row/wave)

__device__ __forceinline__ float qclip(float w) {
  // jnp.clip(jnp.round(w), -128, 127): rintf == round-half-even == jnp.round
  return fminf(fmaxf(rintf(w), -128.0f), 127.0f);
}

// ---------------------------------------------------------------------------
// One fused kernel.
//   blocks [0, EMB_BLOCKS):            embed gather  (copy+dequant one row)
//   blocks [EMB_BLOCKS, +RO_BLOCKS):   readout GEMV  (1 vocab row per wave,
//                                      x-quant computed inline per wave)
// ---------------------------------------------------------------------------
__global__ __launch_bounds__(256) void fused_qembed_kernel(
    const float* __restrict__ W, const float* __restrict__ scales,
    const int* __restrict__ tokens, const float* __restrict__ x,
    float* __restrict__ out_embed, float* __restrict__ out_readout) {
  const int b = blockIdx.x;

  if (b < EMB_BLOCKS) {
    // ---- embed: out_embed[t,:] = qclip(W[tok,:]) * scales[tok] ----
    const int t = b;
    const int tok = tokens[t];
    const float s = scales[tok];
    const float4* __restrict__ wrow =
        reinterpret_cast<const float4*>(W + (size_t)tok * DIM);
    float4* __restrict__ orow =
        reinterpret_cast<float4*>(out_embed + (size_t)t * DIM);
    #pragma unroll
    for (int k = 0; k < DIM / 4 / 256; ++k) {   // 2 iterations
      const int i = threadIdx.x + k * 256;
      float4 w4 = wrow[i];
      float4 r;
      r.x = qclip(w4.x) * s;
      r.y = qclip(w4.y) * s;
      r.z = qclip(w4.z) * s;
      r.w = qclip(w4.w) * s;
      orow[i] = r;
    }
    return;
  }

  // ---- readout: out_readout[row] = scales[row] * dot(qclip(W[row,:]), xq) --
  const int rb = b - EMB_BLOCKS;
  const int wid = threadIdx.x >> 6;
  const int lane = threadIdx.x & 63;
  const int row = rb * 4 + wid;

  // Per-wave inline activation quantization. The wave's 64 lanes × 8 float4
  // cover all DIM=2048 elements of x, so a lane-local max + wave shfl_xor
  // reduce gives the global max|x|. Same fp32 arithmetic in every wave ->
  // identical scale everywhere (deterministic).
  const float4* __restrict__ xv = reinterpret_cast<const float4*>(x);
  float4 xl[8];
  float m = 0.0f;
  #pragma unroll
  for (int k = 0; k < 8; ++k) {
    xl[k] = xv[lane + k * 64];
    m = fmaxf(m, fmaxf(fmaxf(fabsf(xl[k].x), fabsf(xl[k].y)),
                       fmaxf(fabsf(xl[k].z), fabsf(xl[k].w))));
  }
  #pragma unroll
  for (int off = 32; off > 0; off >>= 1) m = fmaxf(m, __shfl_xor(m, off, 64));
  const float scale = fmaxf(m / 127.0f, 1e-12f);
  const float rcp = 1.0f / scale;

  // Quantize this lane's x slice in registers: xq = clip(rint(x/scale))*scale
  #pragma unroll
  for (int k = 0; k < 8; ++k) {
    xl[k].x = fminf(fmaxf(rintf(xl[k].x * rcp), -128.0f), 127.0f) * scale;
    xl[k].y = fminf(fmaxf(rintf(xl[k].y * rcp), -128.0f), 127.0f) * scale;
    xl[k].z = fminf(fmaxf(rintf(xl[k].z * rcp), -128.0f), 127.0f) * scale;
    xl[k].w = fminf(fmaxf(rintf(xl[k].w * rcp), -128.0f), 127.0f) * scale;
  }

  const float4* __restrict__ wrow =
      reinterpret_cast<const float4*>(W + (size_t)row * DIM);
  float acc = 0.0f;
  #pragma unroll
  for (int k = 0; k < 8; ++k) {
    float4 w4 = wrow[lane + k * 64];
    acc += qclip(w4.x) * xl[k].x;
    acc += qclip(w4.y) * xl[k].y;
    acc += qclip(w4.z) * xl[k].z;
    acc += qclip(w4.w) * xl[k].w;
  }
  #pragma unroll
  for (int off = 32; off > 0; off >>= 1) acc += __shfl_down(acc, off, 64);
  if (lane == 0) out_readout[row] = acc * scales[row];
}

// ---------------------------------------------------------------------------
extern "C" void kernel_launch(void* const* d_in, const int* in_sizes, int n_in,
                              void* d_out, int out_size, void* d_ws, size_t ws_size,
                              hipStream_t stream) {
  const float* W      = (const float*)d_in[0];   // [VOCAB, DIM]
  const float* scales = (const float*)d_in[1];   // [VOCAB]
  const int*   tokens = (const int*)d_in[2];     // [NTOK]
  const float* x      = (const float*)d_in[3];   // [DIM]

  float* out_embed   = (float*)d_out;                       // [NTOK, DIM]
  float* out_readout = (float*)d_out + (size_t)NTOK * DIM;  // [VOCAB]

  fused_qembed_kernel<<<EMB_BLOCKS + RO_BLOCKS, 256, 0, stream>>>(
      W, scales, tokens, x, out_embed, out_readout);
}